// Round 5
// baseline (137.486 us; speedup 1.0000x reference)
//
#include <hip/hip_runtime.h>
#include <math.h>

#define B_   2
#define C_   128
#define S_   64
#define H_   128
#define W_   512
#define M_   (S_ * S_)   // 4096
#define MID_ 32
#define EPS_ 1e-5f
#define CAP_ 192         // bucket capacity; E[n]=8 (Poisson), overflow ~impossible

#define KBLK (B_ * H_ * (W_ / 64))   // 2048 k-blocks (64 positions, 4 waves x 16)
#define QBLK (B_ * (M_ / 64))        // 128 q-blocks
#define NTILE (KBLK + QBLK)          // 2176
#define OBLK 4                       // battn overflow tail blocks

typedef __attribute__((ext_vector_type(8))) short short8;
typedef __attribute__((ext_vector_type(4))) float floatx4;

// RNE float->bf16 pair pack (lo = a, hi = b)
__device__ __forceinline__ unsigned bfpair(float a, float b) {
    unsigned ua = __float_as_uint(a); ua += 0x7FFFu + ((ua >> 16) & 1u);
    unsigned ub = __float_as_uint(b); ub += 0x7FFFu + ((ub >> 16) & 1u);
    return (ua >> 16) | (ub & 0xFFFF0000u);
}

// ---------------------------------------------------------------------------
// Projection tile geometry + DMA staging (global_load_lds width 16)
// ---------------------------------------------------------------------------
struct Geo {
    const float* xcol;   // element [c=0][pos0]
    size_t xstr;
    int b, h, pos0;
    bool is_k;
};

__device__ __forceinline__ Geo tile_geo(int t, const float* __restrict__ grd_x,
                                        const float* __restrict__ sat_x) {
    Geo ge;
    ge.is_k = (t < KBLK);
    if (ge.is_k) {
        const int wchunk = t & 7;
        ge.h    = (t >> 3) & (H_ - 1);
        ge.b    = t >> 10;
        ge.pos0 = wchunk * 64;
        ge.xcol = grd_x + ((size_t)ge.b * C_ * H_ + ge.h) * W_ + ge.pos0;
        ge.xstr = (size_t)H_ * W_;
    } else {
        const int qblk = t - KBLK;
        ge.b    = qblk >> 6;
        ge.h    = 0;
        ge.pos0 = (qblk & 63) * 64;
        ge.xcol = sat_x + (size_t)ge.b * C_ * M_ + ge.pos0;
        ge.xstr = (size_t)M_;
    }
    return ge;
}

// wave wv covers c rows {16r + 4wv + (lane>>4)}; swizzle key ((c>>3)&1)==(wv>>1)
// is wave-uniform, applied to the SOURCE index (LDS dest stays linear).
__device__ __forceinline__ void issue_dma(const Geo& ge, float* xs, int lane, int wv) {
    const int swz  = (wv >> 1) << 4;                 // 0 or 16 dwords
    const float* gsrc = ge.xcol + (size_t)(lane >> 4) * ge.xstr
                               + (((lane & 15) * 4) ^ swz);
#pragma unroll
    for (int r = 0; r < 8; ++r) {
        const float* src = gsrc + (size_t)(r * 16 + wv * 4) * ge.xstr;
        float* dst = xs + (r * 16 + wv * 4) * 64;    // wave-uniform base
        __builtin_amdgcn_global_load_lds(
            (const __attribute__((address_space(1))) unsigned int*)src,
            (__attribute__((address_space(3))) unsigned int*)dst,
            16, 0, 0);
    }
}

// ---------------------------------------------------------------------------
// Projection via bf16 hi/lo MFMA, x staged with global_load_lds (width 16).
// Block = 4 waves; wave wv owns the 16-pos tile; one tile per block (max
// block-level parallelism, proven structure). Prep is INLINED: each lane
// computes its 64-element A-fragment (w' = diag(g)W, bf16 hi/lo split) and
// gw/bw partials in registers while the x DMA is in flight — removes the
// serialized prep kernel. kw stored bf16 (RNE); q-path scatters buckets.
// ---------------------------------------------------------------------------
__global__ __launch_bounds__(256) void proj_kernel(
    const float* __restrict__ grd_x,   // [B, C, H, W]
    const float* __restrict__ sat_x,   // [B, C, M]
    const float* __restrict__ ln_k_g, const float* __restrict__ ln_k_b,
    const float* __restrict__ wk, const float* __restrict__ bk,
    const float* __restrict__ ln_q_g, const float* __restrict__ ln_q_b,
    const float* __restrict__ wq, const float* __restrict__ bq,
    const int*   __restrict__ u,       // [B, M]
    unsigned short* __restrict__ kwb,  // [B, W, H, MID] bf16
    float* __restrict__ qv,            // [B, M, MID]
    int* __restrict__ counts,          // [B*W]
    int* __restrict__ bucket,          // [B*W][CAP_]
    int* __restrict__ ocount,          // [1]
    int* __restrict__ olist)           // [B*M]
{
    __shared__ float xs[C_ * 64];      // 32768 B

    const int tid  = threadIdx.x;
    const int lane = tid & 63;
    const int wv   = __builtin_amdgcn_readfirstlane(tid >> 6);  // tile index
    const int quad = lane >> 4;
    const int l16  = lane & 15;
    const int blk  = blockIdx.x;
    const bool is_k = (blk < KBLK);

    const Geo ge = tile_geo(blk, grd_x, sat_x);
    const int pos = ge.pos0 + wv * 16 + l16;

    // ---- DMA staging first: everything below overlaps it ----
    issue_dma(ge, xs, lane, wv);

    // ---- inline prep: A-fragments + gw/bw, all in registers (L1-hot W) ----
    const float* g    = is_k ? ln_k_g : ln_q_g;
    const float* beta = is_k ? ln_k_b : ln_q_b;
    const float* wt   = is_k ? wk     : wq;
    const float* bias = is_k ? bk     : bq;

    short8 ahi[2][4], alo[2][4];
    float gwp0 = 0.f, gwp1 = 0.f, bwp0 = 0.f, bwp1 = 0.f;
#pragma unroll
    for (int kk = 0; kk < 4; ++kk) {
#pragma unroll
        for (int i = 0; i < 8; ++i) {
            const int c   = kk * 32 + quad * 8 + i;
            const float gc = g[c];
            const float bc = beta[c];
            // jt = 0: j = l16
            {
                const float w0 = wt[c * MID_ + l16];
                const float wp = gc * w0;
                const unsigned hb = __float_as_uint(wp) & 0xFFFF0000u;
                ahi[0][kk][i] = (short)(hb >> 16);
                const float r = wp - __uint_as_float(hb);
                alo[0][kk][i] = (short)(__float_as_uint(r) >> 16);
                gwp0 += wp;
                bwp0 = fmaf(bc, w0, bwp0);
            }
            // jt = 1: j = 16 + l16
            {
                const float w1 = wt[c * MID_ + 16 + l16];
                const float wp = gc * w1;
                const unsigned hb = __float_as_uint(wp) & 0xFFFF0000u;
                ahi[1][kk][i] = (short)(hb >> 16);
                const float r = wp - __uint_as_float(hb);
                alo[1][kk][i] = (short)(__float_as_uint(r) >> 16);
                gwp1 += wp;
                bwp1 = fmaf(bc, w1, bwp1);
            }
        }
    }
    // reduce partials over the 4 quads (each quad covered c%32 in [quad*8,quad*8+8))
    gwp0 += __shfl_xor(gwp0, 16, 64); gwp0 += __shfl_xor(gwp0, 32, 64);
    gwp1 += __shfl_xor(gwp1, 16, 64); gwp1 += __shfl_xor(gwp1, 32, 64);
    bwp0 += __shfl_xor(bwp0, 16, 64); bwp0 += __shfl_xor(bwp0, 32, 64);
    bwp1 += __shfl_xor(bwp1, 16, 64); bwp1 += __shfl_xor(bwp1, 32, 64);
    bwp0 += bias[l16];
    bwp1 += bias[16 + l16];
    // redistribute: epilogue lane needs j = jt*16 + quad*4 + r; value sits in
    // lanes with l16 == quad*4 + r (uniform over quads after the xor-reduce).
    float4 gw0, gw1, bw0, bw1;
    gw0.x = __shfl(gwp0, quad * 4 + 0, 64); gw0.y = __shfl(gwp0, quad * 4 + 1, 64);
    gw0.z = __shfl(gwp0, quad * 4 + 2, 64); gw0.w = __shfl(gwp0, quad * 4 + 3, 64);
    gw1.x = __shfl(gwp1, quad * 4 + 0, 64); gw1.y = __shfl(gwp1, quad * 4 + 1, 64);
    gw1.z = __shfl(gwp1, quad * 4 + 2, 64); gw1.w = __shfl(gwp1, quad * 4 + 3, 64);
    bw0.x = __shfl(bwp0, quad * 4 + 0, 64); bw0.y = __shfl(bwp0, quad * 4 + 1, 64);
    bw0.z = __shfl(bwp0, quad * 4 + 2, 64); bw0.w = __shfl(bwp0, quad * 4 + 3, 64);
    bw1.x = __shfl(bwp1, quad * 4 + 0, 64); bw1.y = __shfl(bwp1, quad * 4 + 1, 64);
    bw1.z = __shfl(bwp1, quad * 4 + 2, 64); bw1.w = __shfl(bwp1, quad * 4 + 3, 64);

    __syncthreads();                   // drains DMA (vmcnt) + all waves

    floatx4 acc0 = {0.f, 0.f, 0.f, 0.f};
    floatx4 acc1 = {0.f, 0.f, 0.f, 0.f};
    float p1 = 0.f, p2 = 0.f;

    // B-fragment source: x[c = kk*32 + quad*8 + i][wv*16 + l16], swizzled
    const int rpos = (wv * 16 + l16) ^ ((quad & 1) << 4);
    const float* xsl = xs + quad * 8 * 64 + rpos;

#pragma unroll
    for (int kk = 0; kk < 4; ++kk) {
        const float* xk = xsl + kk * 32 * 64;
        union { short8 v; unsigned u[4]; } bhi, blo;
#pragma unroll
        for (int e = 0; e < 4; ++e) {
            const float x0 = xk[(2 * e)     * 64];
            const float x1 = xk[(2 * e + 1) * 64];
            p1 += x0 + x1;
            p2 = fmaf(x0, x0, p2);
            p2 = fmaf(x1, x1, p2);
            const unsigned b0 = __float_as_uint(x0);
            const unsigned b1 = __float_as_uint(x1);
            bhi.u[e] = (b1 & 0xFFFF0000u) | (b0 >> 16);
            const float r0 = x0 - __uint_as_float(b0 & 0xFFFF0000u);
            const float r1 = x1 - __uint_as_float(b1 & 0xFFFF0000u);
            blo.u[e] = (__float_as_uint(r1) & 0xFFFF0000u) |
                       (__float_as_uint(r0) >> 16);
        }
        acc0 = __builtin_amdgcn_mfma_f32_16x16x32_bf16(ahi[0][kk], bhi.v, acc0, 0, 0, 0);
        acc1 = __builtin_amdgcn_mfma_f32_16x16x32_bf16(ahi[1][kk], bhi.v, acc1, 0, 0, 0);
        acc0 = __builtin_amdgcn_mfma_f32_16x16x32_bf16(ahi[0][kk], blo.v, acc0, 0, 0, 0);
        acc1 = __builtin_amdgcn_mfma_f32_16x16x32_bf16(ahi[1][kk], blo.v, acc1, 0, 0, 0);
        acc0 = __builtin_amdgcn_mfma_f32_16x16x32_bf16(alo[0][kk], bhi.v, acc0, 0, 0, 0);
        acc1 = __builtin_amdgcn_mfma_f32_16x16x32_bf16(alo[1][kk], bhi.v, acc1, 0, 0, 0);
    }

    // LN stats for this pos: reduce over the 4 quads (c-chunks)
    p1 += __shfl_xor(p1, 16, 64);
    p1 += __shfl_xor(p1, 32, 64);
    p2 += __shfl_xor(p2, 16, 64);
    p2 += __shfl_xor(p2, 32, 64);
    const float mean = p1 * (1.f / C_);
    const float rstd = rsqrtf(fmaf(-mean, mean, p2 * (1.f / C_)) + EPS_);

    // epilogue: lane holds D[j][pos], j = jt*16 + quad*4 + reg
    const float o0x = fmaf(rstd, fmaf(-mean, gw0.x, acc0[0]), bw0.x);
    const float o0y = fmaf(rstd, fmaf(-mean, gw0.y, acc0[1]), bw0.y);
    const float o0z = fmaf(rstd, fmaf(-mean, gw0.z, acc0[2]), bw0.z);
    const float o0w = fmaf(rstd, fmaf(-mean, gw0.w, acc0[3]), bw0.w);
    const float o1x = fmaf(rstd, fmaf(-mean, gw1.x, acc1[0]), bw1.x);
    const float o1y = fmaf(rstd, fmaf(-mean, gw1.y, acc1[1]), bw1.y);
    const float o1z = fmaf(rstd, fmaf(-mean, gw1.z, acc1[2]), bw1.z);
    const float o1w = fmaf(rstd, fmaf(-mean, gw1.w, acc1[3]), bw1.w);

    if (is_k) {
        // bf16 store: row of 32 bf16; lane writes j0=quad*4 (+16)
        unsigned short* orow = kwb + (((size_t)ge.b * W_ + pos) * H_ + ge.h) * MID_;
        uint2 u0, u1;
        u0.x = bfpair(o0x, o0y); u0.y = bfpair(o0z, o0w);
        u1.x = bfpair(o1x, o1y); u1.y = bfpair(o1z, o1w);
        *(uint2*)(orow + quad * 4)      = u0;
        *(uint2*)(orow + 16 + quad * 4) = u1;
    } else {
        float* orow = qv + ((size_t)ge.b * M_ + pos) * MID_;
        *(float4*)(orow + quad * 4)      = make_float4(o0x, o0y, o0z, o0w);
        *(float4*)(orow + 16 + quad * 4) = make_float4(o1x, o1y, o1z, o1w);
        // ---- fused bucket scatter (one thread per m) ----
        if (quad == 0) {
            const int bm = ge.b * M_ + pos;
            int w = u[bm];
            w = min(max(w, 0), W_ - 1);
            const int bw = ge.b * W_ + w;
            const int p = atomicAdd(&counts[bw], 1);
            if (p < CAP_) bucket[bw * CAP_ + p] = bm;
            else          olist[atomicAdd(ocount, 1)] = bm;
        }
    }
}

// ---------------------------------------------------------------------------
// Bucketed attention: block per (b,w); each wave hoists its (bf16) k row and
// v values ONCE (unpack outside the m-loop), then loops over the bucket's
// m's. Tail blocks process overflow entries (dead in practice).
// ---------------------------------------------------------------------------
__global__ __launch_bounds__(256) void battn_kernel(
    const float* __restrict__ qv,      // [B, M, MID]
    const unsigned short* __restrict__ kwb, // [B, W, H, MID] bf16
    const float* __restrict__ gh,      // [B, 1, H, W]
    const int*   __restrict__ u,       // [B, M]
    const int*   __restrict__ counts,  // [B*W]
    const int*   __restrict__ bucket,  // [B*W][CAP_]
    const int*   __restrict__ ocount,  // [1]
    const int*   __restrict__ olist,   // [B*M]
    float* __restrict__ out)           // [B, M]
{
    const int blk  = blockIdx.x;
    const int tid  = threadIdx.x;
    const int lane = tid & 63;
    const int wv   = __builtin_amdgcn_readfirstlane(tid >> 6);
    const float sc = 0.17677669529663687f;           // 32^-0.5

    if (blk >= B_ * W_) {
        // ---- overflow tail (runs only if a bucket exceeded CAP_) ----
        const int nof = min(*ocount, B_ * M_);
        const int gwv = (blk - B_ * W_) * 4 + wv;
        for (int i = gwv; i < nof; i += OBLK * 4) {
            const int bm = olist[i];
            const int b  = bm >> 12;
            int w = u[bm];
            w = min(max(w, 0), W_ - 1);
            const unsigned short* kr = kwb + ((size_t)b * W_ + w) * H_ * MID_;
            const float* qr = qv + (size_t)bm * MID_;
            float sq[MID_];
#pragma unroll
            for (int j = 0; j < MID_; ++j) sq[j] = qr[j];
            float d0 = 0.f, d1 = 0.f;
#pragma unroll
            for (int j = 0; j < MID_; ++j) {
                d0 = fmaf(sq[j], __uint_as_float((unsigned)kr[lane * MID_ + j] << 16), d0);
                d1 = fmaf(sq[j], __uint_as_float((unsigned)kr[(lane + 64) * MID_ + j] << 16), d1);
            }
            d0 *= sc; d1 *= sc;
            float mx = fmaxf(d0, d1);
#pragma unroll
            for (int o = 32; o > 0; o >>= 1) mx = fmaxf(mx, __shfl_xor(mx, o, 64));
            const float v0 = gh[((size_t)b * H_ + lane) * W_ + w];
            const float v1 = gh[((size_t)b * H_ + lane + 64) * W_ + w];
            const float e0 = __expf(d0 - mx);
            const float e1 = __expf(d1 - mx);
            float s   = e0 + e1;
            float svv = fmaf(e0, v0, e1 * v1);
#pragma unroll
            for (int o = 32; o > 0; o >>= 1) {
                s   += __shfl_xor(s,   o, 64);
                svv += __shfl_xor(svv, o, 64);
            }
            if (lane == 0) out[bm] = svv / s;
        }
        return;
    }

    const int n = min(counts[blk], CAP_);
    if (wv >= n) return;                             // wave-uniform exit

    const int b = blk >> 9;
    const int w = blk & (W_ - 1);

    // hoist + unpack k rows for h=lane and h=lane+64 (bf16 -> f32, once)
    const uint4* k4 = (const uint4*)(kwb + (size_t)blk * H_ * MID_);
    float ka[32], kb[32];
#pragma unroll
    for (int t = 0; t < 4; ++t) {
        const uint4 ua = k4[lane * 4 + t];
        const uint4 ub = k4[(lane + 64) * 4 + t];
        ka[t*8+0] = __uint_as_float(ua.x << 16); ka[t*8+1] = __uint_as_float(ua.x & 0xFFFF0000u);
        ka[t*8+2] = __uint_as_float(ua.y << 16); ka[t*8+3] = __uint_as_float(ua.y & 0xFFFF0000u);
        ka[t*8+4] = __uint_as_float(ua.z << 16); ka[t*8+5] = __uint_as_float(ua.z & 0xFFFF0000u);
        ka[t*8+6] = __uint_as_float(ua.w << 16); ka[t*8+7] = __uint_as_float(ua.w & 0xFFFF0000u);
        kb[t*8+0] = __uint_as_float(ub.x << 16); kb[t*8+1] = __uint_as_float(ub.x & 0xFFFF0000u);
        kb[t*8+2] = __uint_as_float(ub.y << 16); kb[t*8+3] = __uint_as_float(ub.y & 0xFFFF0000u);
        kb[t*8+4] = __uint_as_float(ub.z << 16); kb[t*8+5] = __uint_as_float(ub.z & 0xFFFF0000u);
        kb[t*8+6] = __uint_as_float(ub.w << 16); kb[t*8+7] = __uint_as_float(ub.w & 0xFFFF0000u);
    }

    const float v0 = gh[((size_t)b * H_ + lane) * W_ + w];
    const float v1 = gh[((size_t)b * H_ + lane + 64) * W_ + w];

    const int* bkt = bucket + (size_t)blk * CAP_;

    for (int i = wv; i < n; i += 4) {
        const int bm = bkt[i];                       // wave-uniform
        const float* qr = qv + (size_t)bm * MID_;
        float sq[MID_];
#pragma unroll
        for (int j = 0; j < MID_; ++j) sq[j] = qr[j];

        float d0 = 0.f, d1 = 0.f;
#pragma unroll
        for (int j = 0; j < MID_; ++j) {
            d0 = fmaf(sq[j], ka[j], d0);
            d1 = fmaf(sq[j], kb[j], d1);
        }
        d0 *= sc; d1 *= sc;

        float mx = fmaxf(d0, d1);
#pragma unroll
        for (int o = 32; o > 0; o >>= 1) mx = fmaxf(mx, __shfl_xor(mx, o, 64));

        const float e0 = __expf(d0 - mx);
        const float e1 = __expf(d1 - mx);
        float s   = e0 + e1;
        float svv = fmaf(e0, v0, e1 * v1);
#pragma unroll
        for (int o = 32; o > 0; o >>= 1) {
            s   += __shfl_xor(s,   o, 64);
            svv += __shfl_xor(svv, o, 64);
        }

        if (lane == 0) out[bm] = svv / s;
    }
}

// ---------------------------------------------------------------------------
extern "C" void kernel_launch(void* const* d_in, const int* in_sizes, int n_in,
                              void* d_out, int out_size, void* d_ws, size_t ws_size,
                              hipStream_t stream) {
    const float* sat_x      = (const float*)d_in[0];
    const float* grd_x      = (const float*)d_in[1];
    const float* grd_height = (const float*)d_in[2];
    const int*   u          = (const int*)d_in[3];
    const float* ln_q_g     = (const float*)d_in[4];
    const float* ln_q_b     = (const float*)d_in[5];
    const float* wq         = (const float*)d_in[6];
    const float* bq         = (const float*)d_in[7];
    const float* ln_k_g     = (const float*)d_in[8];
    const float* ln_k_b     = (const float*)d_in[9];
    const float* wk         = (const float*)d_in[10];
    const float* bk         = (const float*)d_in[11];

    float* out = (float*)d_out;

    // workspace layout
    char* ws = (char*)d_ws;
    unsigned short* kwb = (unsigned short*)ws;                        // 8 MB (bf16)
    float* q       = (float*)(ws + (size_t)8  * 1024 * 1024);         // 1 MB
    int*   counts  = (int*)  (ws + (size_t)9  * 1024 * 1024);         // 4 KB
    int*   ocount  = (int*)  (ws + (size_t)9  * 1024 * 1024 + 4096);  // 4 KB pad
    int*   bucket  = (int*)  (ws + (size_t)9  * 1024 * 1024 + 8192);  // 768 KB
    int*   olist   = bucket + B_ * W_ * CAP_;                          // 32 KB

    // zero counts (4 KB) + pad + ocount in one tiny fill (capture-safe)
    hipMemsetAsync(counts, 0, 8192, stream);

    proj_kernel<<<NTILE, 256, 0, stream>>>(
        grd_x, sat_x,
        ln_k_g, ln_k_b, wk, bk,
        ln_q_g, ln_q_b, wq, bq,
        u, kwb, q, counts, bucket, ocount, olist);
    battn_kernel<<<B_ * W_ + OBLK, 256, 0, stream>>>(
        q, kwb, grd_height, u, counts, bucket, ocount, olist, out);
}

// Round 6
// 130.852 us; speedup vs baseline: 1.0507x; 1.0507x over previous
//
#include <hip/hip_runtime.h>
#include <math.h>

#define B_   2
#define C_   128
#define S_   64
#define H_   128
#define W_   512
#define M_   (S_ * S_)   // 4096
#define MID_ 32
#define EPS_ 1e-5f
#define CAP_ 192         // bucket capacity; E[n]=8 (Poisson), overflow ~impossible

#define KBLK (B_ * H_ * (W_ / 64))   // 2048 k-blocks (64 positions, 4 waves x 16)
#define QBLK (B_ * (M_ / 64))        // 128 q-blocks
#define OBLK 4                       // battn overflow tail blocks

typedef __attribute__((ext_vector_type(8))) short short8;
typedef __attribute__((ext_vector_type(4))) float floatx4;

// RNE float->bf16 pair pack (lo = a, hi = b)
__device__ __forceinline__ unsigned bfpair(float a, float b) {
    unsigned ua = __float_as_uint(a); ua += 0x7FFFu + ((ua >> 16) & 1u);
    unsigned ub = __float_as_uint(b); ub += 0x7FFFu + ((ub >> 16) & 1u);
    return (ua >> 16) | (ub & 0xFFFF0000u);
}

// ---------------------------------------------------------------------------
// Prep: per weight set (block 0 = k, block 1 = q):
//   1. gw = g@W, bw = b@W + bias  -> prepbuf [gw_k|bw_k|gw_q|bw_q] (32 ea)
//   2. bf16 hi/lo split of W' = diag(g)W, packed in MFMA A-fragment order.
//   3. block 0 zeroes bucket counters + overflow counter.
// ---------------------------------------------------------------------------
__global__ __launch_bounds__(256) void prep_kernel(
    const float* __restrict__ ln_k_g, const float* __restrict__ ln_k_b,
    const float* __restrict__ wk, const float* __restrict__ bk,
    const float* __restrict__ ln_q_g, const float* __restrict__ ln_q_b,
    const float* __restrict__ wq, const float* __restrict__ bq,
    float* __restrict__ prepbuf,
    short* __restrict__ wfrag,         // [2 sets][hi 4096 | lo 4096]
    int* __restrict__ counts,          // [B*W]
    int* __restrict__ ocount)          // [1]
{
    const int tid = threadIdx.x;
    const int blk = blockIdx.x;        // 0: k set, 1: q set
    const float* g    = blk ? ln_q_g : ln_k_g;
    const float* bl   = blk ? ln_q_b : ln_k_b;
    const float* wt   = blk ? wq     : wk;
    const float* bias = blk ? bq     : bk;

    __shared__ float pa[256], pb[256];

    // ---- gw/bw ----
    float a = 0.f, c2 = 0.f;
#pragma unroll
    for (int k = 0; k < 16; ++k) {
        const int idx = tid + 256 * k;       // coalesced
        const float wv = wt[idx];
        const int c = idx >> 5;
        a  = fmaf(g[c],  wv, a);
        c2 = fmaf(bl[c], wv, c2);
    }
    pa[tid] = a; pb[tid] = c2;

    if (blk == 0) {                          // zero 1024 counters + ocount
        ((int4*)counts)[tid] = make_int4(0, 0, 0, 0);
        if (tid == 0) *ocount = 0;
    }
    __syncthreads();

    if (tid < 32) {
        float s = 0.f, t = 0.f;
#pragma unroll
        for (int r = 0; r < 8; ++r) { s += pa[tid + 32 * r]; t += pb[tid + 32 * r]; }
        prepbuf[blk * 64 + tid]      = s;
        prepbuf[blk * 64 + 32 + tid] = t + bias[tid];
    }

    // ---- bf16 hi/lo fragment tables ----
    short* whiT = wfrag + blk * 8192;
    short* wloT = whiT + 4096;
#pragma unroll
    for (int e = 0; e < 16; ++e) {
        const int idx = tid * 16 + e;
        const int i    = idx & 7;
        const int ln   = (idx >> 3) & 63;
        const int kk   = (idx >> 9) & 3;
        const int jt   = idx >> 11;
        const int c = kk * 32 + (ln >> 4) * 8 + i;
        const int j = jt * 16 + (ln & 15);
        const float wp = g[c] * wt[c * MID_ + j];
        const unsigned bbits = __float_as_uint(wp);
        const unsigned hb = bbits & 0xFFFF0000u;
        whiT[idx] = (short)(hb >> 16);
        const float r = wp - __uint_as_float(hb);
        wloT[idx] = (short)(__float_as_uint(r) >> 16);
    }
}

// ---------------------------------------------------------------------------
// Projection via bf16 hi/lo MFMA, x staged with global_load_lds (width 16).
// Block = 4 waves; wave wv owns the 16-pos tile. LDS layout [c][64] with
// free swizzle pos^16*((c>>3)&1): wave-uniform on the DMA (applied to the
// SOURCE index, keeping lane*16 contiguity), quad&1 on reads (2-way = free).
// kw output stored bf16 (RNE). q-path scatters bm into buckets.
// ---------------------------------------------------------------------------
__global__ __launch_bounds__(256) void proj_kernel(
    const float* __restrict__ grd_x,   // [B, C, H, W]
    const float* __restrict__ sat_x,   // [B, C, M]
    const float* __restrict__ prepbuf, // [4][32]
    const short* __restrict__ wfrag,   // [2][2][4096]
    const int*   __restrict__ u,       // [B, M]
    unsigned short* __restrict__ kwb,  // [B, W, H, MID] bf16
    float* __restrict__ qv,            // [B, M, MID]
    int* __restrict__ counts,          // [B*W]
    int* __restrict__ bucket,          // [B*W][CAP_]
    int* __restrict__ ocount,          // [1]
    int* __restrict__ olist)           // [B*M]
{
    __shared__ float xs[C_ * 64];      // 32768 B -> 5 blocks/CU

    const int tid  = threadIdx.x;
    const int lane = tid & 63;
    const int wv   = __builtin_amdgcn_readfirstlane(tid >> 6);  // tile index
    const int quad = lane >> 4;
    const int l16  = lane & 15;
    const int blk  = blockIdx.x;
    const bool is_k = (blk < KBLK);

    // geometry
    int b, h = 0, pos0;
    const float* xcol;                 // element [c=0][pos0]
    size_t xstr;
    if (is_k) {
        const int wchunk = blk & 7;
        h    = (blk >> 3) & (H_ - 1);
        b    = blk >> 10;
        pos0 = wchunk * 64;
        xcol = grd_x + ((size_t)b * C_ * H_ + h) * W_ + pos0;
        xstr = (size_t)H_ * W_;
    } else {
        const int qblk = blk - KBLK;
        b    = qblk >> 6;
        pos0 = (qblk & 63) * 64;
        xcol = sat_x + (size_t)b * C_ * M_ + pos0;
        xstr = (size_t)M_;
    }
    const int pos = pos0 + wv * 16 + l16;

    // ---- DMA staging: wave wv covers c rows {16r + 4wv + (lane>>4)} ----
    // swizzle key for these c's: ((c>>3)&1) == (wv>>1), wave-uniform.
    {
        const int swz  = (wv >> 1) << 4;                 // 0 or 16 dwords
        const float* gsrc = xcol + (size_t)(lane >> 4) * xstr
                                 + (((lane & 15) * 4) ^ swz);
#pragma unroll
        for (int r = 0; r < 8; ++r) {
            const float* src = gsrc + (size_t)(r * 16 + wv * 4) * xstr;
            float* dst = xs + (r * 16 + wv * 4) * 64;    // wave-uniform base
            __builtin_amdgcn_global_load_lds(
                (const __attribute__((address_space(1))) unsigned int*)src,
                (__attribute__((address_space(3))) unsigned int*)dst,
                16, 0, 0);
        }
    }

    // ---- A-fragments (weights), pre-packed, L1/L2-hot (overlap with DMA) --
    const short* whiT = wfrag + (is_k ? 0 : 8192);
    const short* wloT = whiT + 4096;
    short8 ahi[2][4], alo[2][4];
#pragma unroll
    for (int jt = 0; jt < 2; ++jt)
#pragma unroll
        for (int kk = 0; kk < 4; ++kk) {
            const int off = ((jt * 4 + kk) * 64 + lane) * 8;
            ahi[jt][kk] = *(const short8*)(whiT + off);
            alo[jt][kk] = *(const short8*)(wloT + off);
        }

    // gw/bw for this lane's output rows
    const int setoff = is_k ? 0 : 64;
    const float4 gw0 = *(const float4*)(prepbuf + setoff + quad * 4);
    const float4 bw0 = *(const float4*)(prepbuf + setoff + 32 + quad * 4);
    const float4 gw1 = *(const float4*)(prepbuf + setoff + 16 + quad * 4);
    const float4 bw1 = *(const float4*)(prepbuf + setoff + 48 + quad * 4);

    __syncthreads();                   // drains DMA (vmcnt) + all waves

    floatx4 acc0 = {0.f, 0.f, 0.f, 0.f};
    floatx4 acc1 = {0.f, 0.f, 0.f, 0.f};
    float p1 = 0.f, p2 = 0.f;

    // B-fragment source: x[c = kk*32 + quad*8 + i][wv*16 + l16], swizzled
    const int rpos = (wv * 16 + l16) ^ ((quad & 1) << 4);
    const float* xsl = xs + quad * 8 * 64 + rpos;

#pragma unroll
    for (int kk = 0; kk < 4; ++kk) {
        const float* xk = xsl + kk * 32 * 64;
        union { short8 v; unsigned u[4]; } bhi, blo;
#pragma unroll
        for (int e = 0; e < 4; ++e) {
            const float x0 = xk[(2 * e)     * 64];
            const float x1 = xk[(2 * e + 1) * 64];
            p1 += x0 + x1;
            p2 = fmaf(x0, x0, p2);
            p2 = fmaf(x1, x1, p2);
            const unsigned b0 = __float_as_uint(x0);
            const unsigned b1 = __float_as_uint(x1);
            bhi.u[e] = (b1 & 0xFFFF0000u) | (b0 >> 16);
            const float r0 = x0 - __uint_as_float(b0 & 0xFFFF0000u);
            const float r1 = x1 - __uint_as_float(b1 & 0xFFFF0000u);
            blo.u[e] = (__float_as_uint(r1) & 0xFFFF0000u) |
                       (__float_as_uint(r0) >> 16);
        }
        acc0 = __builtin_amdgcn_mfma_f32_16x16x32_bf16(ahi[0][kk], bhi.v, acc0, 0, 0, 0);
        acc1 = __builtin_amdgcn_mfma_f32_16x16x32_bf16(ahi[1][kk], bhi.v, acc1, 0, 0, 0);
        acc0 = __builtin_amdgcn_mfma_f32_16x16x32_bf16(ahi[0][kk], blo.v, acc0, 0, 0, 0);
        acc1 = __builtin_amdgcn_mfma_f32_16x16x32_bf16(ahi[1][kk], blo.v, acc1, 0, 0, 0);
        acc0 = __builtin_amdgcn_mfma_f32_16x16x32_bf16(alo[0][kk], bhi.v, acc0, 0, 0, 0);
        acc1 = __builtin_amdgcn_mfma_f32_16x16x32_bf16(alo[1][kk], bhi.v, acc1, 0, 0, 0);
    }

    // LN stats for this pos: reduce over the 4 quads (c-chunks)
    p1 += __shfl_xor(p1, 16, 64);
    p1 += __shfl_xor(p1, 32, 64);
    p2 += __shfl_xor(p2, 16, 64);
    p2 += __shfl_xor(p2, 32, 64);
    const float mean = p1 * (1.f / C_);
    const float rstd = rsqrtf(fmaf(-mean, mean, p2 * (1.f / C_)) + EPS_);

    // epilogue: lane holds D[j][pos], j = jt*16 + quad*4 + reg
    float o0x = fmaf(rstd, fmaf(-mean, gw0.x, acc0[0]), bw0.x);
    float o0y = fmaf(rstd, fmaf(-mean, gw0.y, acc0[1]), bw0.y);
    float o0z = fmaf(rstd, fmaf(-mean, gw0.z, acc0[2]), bw0.z);
    float o0w = fmaf(rstd, fmaf(-mean, gw0.w, acc0[3]), bw0.w);
    float o1x = fmaf(rstd, fmaf(-mean, gw1.x, acc1[0]), bw1.x);
    float o1y = fmaf(rstd, fmaf(-mean, gw1.y, acc1[1]), bw1.y);
    float o1z = fmaf(rstd, fmaf(-mean, gw1.z, acc1[2]), bw1.z);
    float o1w = fmaf(rstd, fmaf(-mean, gw1.w, acc1[3]), bw1.w);

    if (is_k) {
        // bf16 store: row of 32 bf16; lane writes j0=quad*4 (+16)
        unsigned short* orow = kwb + (((size_t)b * W_ + pos) * H_ + h) * MID_;
        uint2 u0, u1;
        u0.x = bfpair(o0x, o0y); u0.y = bfpair(o0z, o0w);
        u1.x = bfpair(o1x, o1y); u1.y = bfpair(o1z, o1w);
        *(uint2*)(orow + quad * 4)      = u0;
        *(uint2*)(orow + 16 + quad * 4) = u1;
    } else {
        float* orow = qv + ((size_t)b * M_ + pos) * MID_;
        *(float4*)(orow + quad * 4)      = make_float4(o0x, o0y, o0z, o0w);
        *(float4*)(orow + 16 + quad * 4) = make_float4(o1x, o1y, o1z, o1w);
        // ---- fused bucket scatter (one thread per m) ----
        if (quad == 0) {
            const int bm = b * M_ + pos;
            int w = u[bm];
            w = min(max(w, 0), W_ - 1);
            const int bw = b * W_ + w;
            const int p = atomicAdd(&counts[bw], 1);
            if (p < CAP_) bucket[bw * CAP_ + p] = bm;
            else          olist[atomicAdd(ocount, 1)] = bm;
        }
    }
}

// ---------------------------------------------------------------------------
// Bucketed attention: block per (b,w); each wave hoists its (bf16) k row and
// v values ONCE (unpack outside the m-loop), then loops over the bucket's
// m's. Bucket entry is scalarized (wave-uniform) so q-row loads are s_loads.
// Tail blocks process overflow entries (dead in practice).
// ---------------------------------------------------------------------------
__global__ __launch_bounds__(256) void battn_kernel(
    const float* __restrict__ qv,      // [B, M, MID]
    const unsigned short* __restrict__ kwb, // [B, W, H, MID] bf16
    const float* __restrict__ gh,      // [B, 1, H, W]
    const int*   __restrict__ u,       // [B, M]
    const int*   __restrict__ counts,  // [B*W]
    const int*   __restrict__ bucket,  // [B*W][CAP_]
    const int*   __restrict__ ocount,  // [1]
    const int*   __restrict__ olist,   // [B*M]
    float* __restrict__ out)           // [B, M]
{
    const int blk  = blockIdx.x;
    const int tid  = threadIdx.x;
    const int lane = tid & 63;
    const int wv   = __builtin_amdgcn_readfirstlane(tid >> 6);
    const float sc = 0.17677669529663687f;           // 32^-0.5

    if (blk >= B_ * W_) {
        // ---- overflow tail (runs only if a bucket exceeded CAP_) ----
        const int nof = min(*ocount, B_ * M_);
        const int gwv = (blk - B_ * W_) * 4 + wv;
        for (int i = gwv; i < nof; i += OBLK * 4) {
            const int bm = olist[i];
            const int b  = bm >> 12;
            int w = u[bm];
            w = min(max(w, 0), W_ - 1);
            const unsigned short* kr = kwb + ((size_t)b * W_ + w) * H_ * MID_;
            const float* qr = qv + (size_t)bm * MID_;
            float sq[MID_];
#pragma unroll
            for (int j = 0; j < MID_; ++j) sq[j] = qr[j];
            float d0 = 0.f, d1 = 0.f;
#pragma unroll
            for (int j = 0; j < MID_; ++j) {
                d0 = fmaf(sq[j], __uint_as_float((unsigned)kr[lane * MID_ + j] << 16), d0);
                d1 = fmaf(sq[j], __uint_as_float((unsigned)kr[(lane + 64) * MID_ + j] << 16), d1);
            }
            d0 *= sc; d1 *= sc;
            float mx = fmaxf(d0, d1);
#pragma unroll
            for (int o = 32; o > 0; o >>= 1) mx = fmaxf(mx, __shfl_xor(mx, o, 64));
            const float v0 = gh[((size_t)b * H_ + lane) * W_ + w];
            const float v1 = gh[((size_t)b * H_ + lane + 64) * W_ + w];
            const float e0 = __expf(d0 - mx);
            const float e1 = __expf(d1 - mx);
            float s   = e0 + e1;
            float svv = fmaf(e0, v0, e1 * v1);
#pragma unroll
            for (int o = 32; o > 0; o >>= 1) {
                s   += __shfl_xor(s,   o, 64);
                svv += __shfl_xor(svv, o, 64);
            }
            if (lane == 0) out[bm] = svv / s;
        }
        return;
    }

    const int n = min(counts[blk], CAP_);
    if (wv >= n) return;                             // wave-uniform exit

    const int b = blk >> 9;
    const int w = blk & (W_ - 1);

    // hoist + unpack k rows for h=lane and h=lane+64 (bf16 -> f32, once)
    const uint4* k4 = (const uint4*)(kwb + (size_t)blk * H_ * MID_);
    float ka[32], kb[32];
#pragma unroll
    for (int t = 0; t < 4; ++t) {
        const uint4 ua = k4[lane * 4 + t];
        const uint4 ub = k4[(lane + 64) * 4 + t];
        ka[t*8+0] = __uint_as_float(ua.x << 16); ka[t*8+1] = __uint_as_float(ua.x & 0xFFFF0000u);
        ka[t*8+2] = __uint_as_float(ua.y << 16); ka[t*8+3] = __uint_as_float(ua.y & 0xFFFF0000u);
        ka[t*8+4] = __uint_as_float(ua.z << 16); ka[t*8+5] = __uint_as_float(ua.z & 0xFFFF0000u);
        ka[t*8+6] = __uint_as_float(ua.w << 16); ka[t*8+7] = __uint_as_float(ua.w & 0xFFFF0000u);
        kb[t*8+0] = __uint_as_float(ub.x << 16); kb[t*8+1] = __uint_as_float(ub.x & 0xFFFF0000u);
        kb[t*8+2] = __uint_as_float(ub.y << 16); kb[t*8+3] = __uint_as_float(ub.y & 0xFFFF0000u);
        kb[t*8+4] = __uint_as_float(ub.z << 16); kb[t*8+5] = __uint_as_float(ub.z & 0xFFFF0000u);
        kb[t*8+6] = __uint_as_float(ub.w << 16); kb[t*8+7] = __uint_as_float(ub.w & 0xFFFF0000u);
    }

    const float v0 = gh[((size_t)b * H_ + lane) * W_ + w];
    const float v1 = gh[((size_t)b * H_ + lane + 64) * W_ + w];

    const int* bkt = bucket + (size_t)blk * CAP_;

    for (int i = wv; i < n; i += 4) {
        // wave-uniform bucket entry -> scalarize so q-row loads become s_loads
        const int bm = __builtin_amdgcn_readfirstlane(bkt[i]);
        const float* qr = qv + (size_t)bm * MID_;
        float sq[MID_];
#pragma unroll
        for (int j = 0; j < MID_; ++j) sq[j] = qr[j];

        float d0 = 0.f, d1 = 0.f;
#pragma unroll
        for (int j = 0; j < MID_; ++j) {
            d0 = fmaf(sq[j], ka[j], d0);
            d1 = fmaf(sq[j], kb[j], d1);
        }
        d0 *= sc; d1 *= sc;

        float mx = fmaxf(d0, d1);
#pragma unroll
        for (int o = 32; o > 0; o >>= 1) mx = fmaxf(mx, __shfl_xor(mx, o, 64));

        const float e0 = __expf(d0 - mx);
        const float e1 = __expf(d1 - mx);
        float s   = e0 + e1;
        float svv = fmaf(e0, v0, e1 * v1);
#pragma unroll
        for (int o = 32; o > 0; o >>= 1) {
            s   += __shfl_xor(s,   o, 64);
            svv += __shfl_xor(svv, o, 64);
        }

        if (lane == 0) out[bm] = svv / s;
    }
}

// ---------------------------------------------------------------------------
extern "C" void kernel_launch(void* const* d_in, const int* in_sizes, int n_in,
                              void* d_out, int out_size, void* d_ws, size_t ws_size,
                              hipStream_t stream) {
    const float* sat_x      = (const float*)d_in[0];
    const float* grd_x      = (const float*)d_in[1];
    const float* grd_height = (const float*)d_in[2];
    const int*   u          = (const int*)d_in[3];
    const float* ln_q_g     = (const float*)d_in[4];
    const float* ln_q_b     = (const float*)d_in[5];
    const float* wq         = (const float*)d_in[6];
    const float* bq         = (const float*)d_in[7];
    const float* ln_k_g     = (const float*)d_in[8];
    const float* ln_k_b     = (const float*)d_in[9];
    const float* wk         = (const float*)d_in[10];
    const float* bk         = (const float*)d_in[11];

    float* out = (float*)d_out;

    // workspace layout
    char* ws = (char*)d_ws;
    unsigned short* kwb = (unsigned short*)ws;                        // 8 MB (bf16)
    float* q       = (float*)(ws + (size_t)8  * 1024 * 1024);         // 1 MB
    int*   counts  = (int*)  (ws + (size_t)9  * 1024 * 1024);         // 4 KB
    int*   ocount  = (int*)  (ws + (size_t)9  * 1024 * 1024 + 4096);  // 4 KB pad
    int*   bucket  = (int*)  (ws + (size_t)9  * 1024 * 1024 + 8192);  // 768 KB
    int*   olist   = bucket + B_ * W_ * CAP_;                          // 32 KB
    float* prepbuf = (float*)(ws + (size_t)10 * 1024 * 1024);         // 512 B
    short* wfrag   = (short*)(ws + (size_t)10 * 1024 * 1024 + 4096);  // 32 KB

    prep_kernel<<<2, 256, 0, stream>>>(
        ln_k_g, ln_k_b, wk, bk, ln_q_g, ln_q_b, wq, bq,
        prepbuf, wfrag, counts, ocount);
    proj_kernel<<<KBLK + QBLK, 256, 0, stream>>>(
        grd_x, sat_x, prepbuf, wfrag, u, kwb, q, counts, bucket, ocount, olist);
    battn_kernel<<<B_ * W_ + OBLK, 256, 0, stream>>>(
        q, kwb, grd_height, u, counts, bucket, ocount, olist, out);
}